// Round 2
// baseline (573.841 us; speedup 1.0000x reference)
//
#include <hip/hip_runtime.h>

// Mesh2: out3 = [out1||out2] @ W_comb^T + b_comb ; out4 = mean(self+3nbrs) @ W_agg^T + b_agg
// Strategy: bf16 MFMA (16x16x32), fused gather+GEMM, weights pre-packed to fragment layout.
// R1 fix: neighbour is pushed by the harness as int32 (NOT int64) — int64 read was OOB -> abort.

typedef __bf16 bf16x8 __attribute__((ext_vector_type(8)));
typedef float f32x4 __attribute__((ext_vector_type(4)));

#define N_NODES 200000
#define BM 32
#define ROWC 520  // 512 + 8 pad (bf16 elems) -> row stride 1040 B, 16B-aligned, conflict-free
#define ROWA 264  // 256 + 8 pad

__device__ __forceinline__ unsigned short f2bf(float x) {
  union { float f; unsigned int u; } v; v.f = x;
  return (unsigned short)((v.u + 0x7FFFu + ((v.u >> 16) & 1u)) >> 16);  // RNE
}

__device__ __forceinline__ void st_bf4(unsigned short* p, float4 f) {
  uint2 w;
  w.x = (unsigned int)f2bf(f.x) | ((unsigned int)f2bf(f.y) << 16);
  w.y = (unsigned int)f2bf(f.z) | ((unsigned int)f2bf(f.w) << 16);
  *reinterpret_cast<uint2*>(p) = w;
}

// Pack W (f32, row-major [O][K]) into bf16 MFMA-B-fragment-linear layout:
// for tile (nt,kt): lane l holds W[nt*16 + (l&15)][kt*32 + (l>>4)*8 + j], j=0..7,
// stored contiguously at P[tile*512 + l*8 + j].
__global__ void pack_w_kernel(const float* __restrict__ Wc,
                              const float* __restrict__ Wa,
                              unsigned short* __restrict__ Pc,
                              unsigned short* __restrict__ Pa) {
  int t = blockIdx.x * 256 + threadIdx.x;
  if (t >= (512 + 256) * 64) return;   // 512 comb tiles + 256 agg tiles, 64 lanes each
  int lane = t & 63;
  int tile = t >> 6;
  const float* W;
  unsigned short* P;
  int K, kt_n;
  if (tile < 512) { W = Wc; P = Pc; K = 512; kt_n = 16; }
  else { tile -= 512; W = Wa; P = Pa; K = 256; kt_n = 8; }
  int nt = tile / kt_n;
  int kt = tile - nt * kt_n;
  int row = nt * 16 + (lane & 15);
  int k0 = kt * 32 + (lane >> 4) * 8;
  const float* src = W + (size_t)row * K + k0;
  unsigned short* dst = P + (size_t)tile * 512 + lane * 8;
#pragma unroll
  for (int j = 0; j < 8; ++j) dst[j] = f2bf(src[j]);
}

__global__ __launch_bounds__(512, 4) void mesh_fused_kernel(
    const float* __restrict__ out1,
    const float* __restrict__ out2,
    const int* __restrict__ nbr,
    const unsigned short* __restrict__ Pc,
    const unsigned short* __restrict__ Pa,
    const float* __restrict__ b_comb,
    const float* __restrict__ b_agg,
    float* __restrict__ outp) {
  __shared__ unsigned short Acomb[BM * ROWC];
  __shared__ unsigned short Aagg[BM * ROWA];

  const int tid = threadIdx.x;
  const long long node0 = (long long)blockIdx.x * BM;

  // ---------------- stage: 16 threads per node ----------------
  {
    const int ln = tid >> 4;    // local node 0..31
    const int c16 = tid & 15;   // chunk lane
    const long long gn = node0 + ln;
    const long long nb = gn * 3;
    long long i0 = nbr[nb + 0];
    long long i1 = nbr[nb + 1];
    long long i2 = nbr[nb + 2];
    // clamp: insurance against any index-dtype surprise (no-op for valid data)
    i0 = i0 < 0 ? 0 : (i0 >= N_NODES ? N_NODES - 1 : i0);
    i1 = i1 < 0 ? 0 : (i1 >= N_NODES ? N_NODES - 1 : i1);
    i2 = i2 < 0 ? 0 : (i2 >= N_NODES ? N_NODES - 1 : i2);
    const float4* r1 = reinterpret_cast<const float4*>(out1 + gn * 256);
    const float4* r2 = reinterpret_cast<const float4*>(out2 + gn * 256);
    const float4* g0 = reinterpret_cast<const float4*>(out2 + i0 * 256);
    const float4* g1 = reinterpret_cast<const float4*>(out2 + i1 * 256);
    const float4* g2 = reinterpret_cast<const float4*>(out2 + i2 * 256);
#pragma unroll
    for (int r = 0; r < 4; ++r) {
      const int c = c16 + 16 * r;  // float4 index within the 64-chunk row
      float4 f1 = r1[c];
      float4 f2 = r2[c];
      float4 n0 = g0[c];
      float4 n1 = g1[c];
      float4 n2 = g2[c];
      float4 ag;
      ag.x = (f2.x + n0.x + n1.x + n2.x) * 0.25f;
      ag.y = (f2.y + n0.y + n1.y + n2.y) * 0.25f;
      ag.z = (f2.z + n0.z + n1.z + n2.z) * 0.25f;
      ag.w = (f2.w + n0.w + n1.w + n2.w) * 0.25f;
      st_bf4(&Acomb[ln * ROWC + c * 4], f1);          // cols 0..255   = out1
      st_bf4(&Acomb[ln * ROWC + 256 + c * 4], f2);    // cols 256..511 = out2
      st_bf4(&Aagg[ln * ROWA + c * 4], ag);           // agg
    }
  }
  __syncthreads();

  // ---------------- compute: wave w owns cols [64w, 64w+64) of out3 AND out4 ----------------
  const int wave = tid >> 6;  // 0..7
  const int lane = tid & 63;
  const int l15 = lane & 15;
  const int l4 = lane >> 4;

  f32x4 acc3[2][4], acc4[2][4];
#pragma unroll
  for (int m = 0; m < 2; ++m)
#pragma unroll
    for (int n = 0; n < 4; ++n) {
      acc3[m][n] = (f32x4){0.f, 0.f, 0.f, 0.f};
      acc4[m][n] = (f32x4){0.f, 0.f, 0.f, 0.f};
    }

  const int nt0 = wave * 4;  // first 16-col tile of this wave

  // out3: K = 512 (16 k-tiles of 32)
  {
    const unsigned short* pc = Pc + (size_t)nt0 * 16 * 512 + lane * 8;
    const unsigned short* a_base = &Acomb[(size_t)l15 * ROWC + l4 * 8];
#pragma unroll
    for (int kt = 0; kt < 16; ++kt) {
      bf16x8 a0 = *reinterpret_cast<const bf16x8*>(a_base + kt * 32);
      bf16x8 a1 = *reinterpret_cast<const bf16x8*>(a_base + 16 * ROWC + kt * 32);
#pragma unroll
      for (int n = 0; n < 4; ++n) {
        bf16x8 b = *reinterpret_cast<const bf16x8*>(pc + ((size_t)n * 16 + kt) * 512);
        acc3[0][n] = __builtin_amdgcn_mfma_f32_16x16x32_bf16(a0, b, acc3[0][n], 0, 0, 0);
        acc3[1][n] = __builtin_amdgcn_mfma_f32_16x16x32_bf16(a1, b, acc3[1][n], 0, 0, 0);
      }
    }
  }

  // out4: K = 256 (8 k-tiles of 32)
  {
    const unsigned short* pa = Pa + (size_t)nt0 * 8 * 512 + lane * 8;
    const unsigned short* a_base = &Aagg[(size_t)l15 * ROWA + l4 * 8];
#pragma unroll
    for (int kt = 0; kt < 8; ++kt) {
      bf16x8 a0 = *reinterpret_cast<const bf16x8*>(a_base + kt * 32);
      bf16x8 a1 = *reinterpret_cast<const bf16x8*>(a_base + 16 * ROWA + kt * 32);
#pragma unroll
      for (int n = 0; n < 4; ++n) {
        bf16x8 b = *reinterpret_cast<const bf16x8*>(pa + ((size_t)n * 8 + kt) * 512);
        acc4[0][n] = __builtin_amdgcn_mfma_f32_16x16x32_bf16(a0, b, acc4[0][n], 0, 0, 0);
        acc4[1][n] = __builtin_amdgcn_mfma_f32_16x16x32_bf16(a1, b, acc4[1][n], 0, 0, 0);
      }
    }
  }

  // ---------------- epilogue: D[row=(l>>4)*4+r][col=l&15] (m89-verified layout) ----------------
  float* o3 = outp;
  float* o4 = outp + (size_t)N_NODES * 512;
#pragma unroll
  for (int n = 0; n < 4; ++n) {
    const int col = wave * 64 + n * 16 + l15;
    const float bc = b_comb[col];
    const float ba = b_agg[col];
#pragma unroll
    for (int m = 0; m < 2; ++m) {
#pragma unroll
      for (int r = 0; r < 4; ++r) {
        const long long row = node0 + m * 16 + l4 * 4 + r;
        o3[row * 512 + col] = acc3[m][n][r] + bc;
        o4[row * 512 + col] = acc4[m][n][r] + ba;
      }
    }
  }
}

extern "C" void kernel_launch(void* const* d_in, const int* in_sizes, int n_in,
                              void* d_out, int out_size, void* d_ws, size_t ws_size,
                              hipStream_t stream) {
  const float* out1 = (const float*)d_in[0];
  const float* out2 = (const float*)d_in[1];
  const int* nbr = (const int*)d_in[2];          // harness pushes integers as int32
  const float* Wc = (const float*)d_in[3];
  const float* bc = (const float*)d_in[4];
  const float* Wa = (const float*)d_in[5];
  const float* ba = (const float*)d_in[6];

  unsigned short* Pc = (unsigned short*)d_ws;            // 512*512 bf16 = 512 KB
  unsigned short* Pa = Pc + 512 * 512;                   // 512*256 bf16 = 256 KB

  pack_w_kernel<<<192, 256, 0, stream>>>(Wc, Wa, Pc, Pa);
  mesh_fused_kernel<<<N_NODES / BM, 512, 0, stream>>>(out1, out2, nbr, Pc, Pa, bc, ba,
                                                      (float*)d_out);
}